// Round 5
// baseline (218.072 us; speedup 1.0000x reference)
//
#include <hip/hip_runtime.h>
#include <math.h>

#define NSEQ 2048
#define EPSF 1e-8f
#define INV2R2 0.35355339059327373f
#define INVR2  0.7071067811865476f
#define NTB 1024        // kB: 16 waves, 4 per SIMD

// ---------- compile-time Leray conv taps (radius 32) ----------
// Jacobi: p_{n+1} = M p_n - 0.5 b, p_0=0, 50 iters => p = K*b, K circulant |j|<=49.
// leray(u) = conv(LK, u), LK_o = delta_o - (K_{o+1}-2K_o+K_{o-1}); symmetric.
// |LK_o| < ~3e-6 for |o|>32 (binomial tail) -> radius-32 truncation error ~1e-8.
struct Taps65 { float v[65]; };

constexpr Taps65 make_taps65() {
  Taps65 t{};
  double K[99] = {};
  for (int j = -49; j <= 49; ++j) {
    int aj = j < 0 ? -j : j;
    double term = 1.0;
    for (int q = 0; q < aj; ++q) term *= 0.5;
    double sum = term;
    for (int i = aj + 2; i <= 49; i += 2) {
      int m = (i + j) / 2;
      term *= (double)((i - 1) * i) / (4.0 * (double)m * (double)(i - m));
      sum += term;
    }
    K[j + 49] = -0.5 * sum;
  }
  for (int o = -32; o <= 32; ++o) {
    double km1 = K[o - 1 + 49], k0 = K[o + 49], kp1 = K[o + 1 + 49];
    double T = kp1 - 2.0 * k0 + km1;
    t.v[o + 32] = (float)(((o == 0) ? 1.0 : 0.0) - T);
  }
  return t;
}
constexpr Taps65 LK65 = make_taps65();

// ---------- reduction helpers (1024 threads = 16 waves) ----------
__device__ __forceinline__ float wave_sum(float x) {
#pragma unroll
  for (int m = 1; m < 64; m <<= 1) x += __shfl_xor(x, m, 64);
  return x;
}
__device__ __forceinline__ float wave_max(float x) {
#pragma unroll
  for (int m = 1; m < 64; m <<= 1) x = fmaxf(x, __shfl_xor(x, m, 64));
  return x;
}
__device__ __forceinline__ float block_sum(float x, float* red, int tid, int& gen) {
  float w = wave_sum(x);
  int slot = (gen & 7) << 5; gen++;
  if ((tid & 63) == 0) red[slot + (tid >> 6)] = w;
  __syncthreads();
  float4 a = *(float4*)(red + slot),      bq = *(float4*)(red + slot + 4),
         c = *(float4*)(red + slot + 8),  d  = *(float4*)(red + slot + 12);
  return ((a.x + a.y) + (a.z + a.w)) + ((bq.x + bq.y) + (bq.z + bq.w)) +
         ((c.x + c.y) + (c.z + c.w)) + ((d.x + d.y) + (d.z + d.w));
}
__device__ __forceinline__ void block_sum2(float a, float b, float* red, int tid, int& gen,
                                           float& oa, float& ob) {
  float wa = wave_sum(a), wb = wave_sum(b);
  int slot = (gen & 7) << 5; gen++;
  if ((tid & 63) == 0) { int w = tid >> 6; red[slot + w] = wa; red[slot + 16 + w] = wb; }
  __syncthreads();
  float4 a0 = *(float4*)(red + slot),      a1 = *(float4*)(red + slot + 4),
         a2 = *(float4*)(red + slot + 8),  a3 = *(float4*)(red + slot + 12);
  float4 b0 = *(float4*)(red + slot + 16), b1 = *(float4*)(red + slot + 20),
         b2 = *(float4*)(red + slot + 24), b3 = *(float4*)(red + slot + 28);
  oa = ((a0.x + a0.y) + (a0.z + a0.w)) + ((a1.x + a1.y) + (a1.z + a1.w)) +
       ((a2.x + a2.y) + (a2.z + a2.w)) + ((a3.x + a3.y) + (a3.z + a3.w));
  ob = ((b0.x + b0.y) + (b0.z + b0.w)) + ((b1.x + b1.y) + (b1.z + b1.w)) +
       ((b2.x + b2.y) + (b2.z + b2.w)) + ((b3.x + b3.y) + (b3.z + b3.w));
}
__device__ __forceinline__ float sgnf(float x) {
  return (x > 0.f) ? 1.f : ((x < 0.f) ? -1.f : 0.f);
}

// ---------- conv: stage (all 1024), compute on waves 0-7 at 4 outputs/thread ----------
template <bool DOMAX>
__device__ __forceinline__ void conv_exec(float in0, float in1, float* __restrict__ cb,
                                          float* __restrict__ cb2, float* __restrict__ red2,
                                          int tid) {
  *(float2*)(cb + 2 * tid) = make_float2(in0, in1);
  __syncthreads();
  if (tid < 512) {
    const int base = tid << 2;
    float acc[4] = {0.f, 0.f, 0.f, 0.f};
#pragma unroll
    for (int m = 0; m < 17; ++m) {
      const int idx = (base - 32 + 4 * m) & (NSEQ - 1);
      const float4 c4 = *(const float4*)(cb + idx);
      const float cv[4] = {c4.x, c4.y, c4.z, c4.w};
#pragma unroll
      for (int jj = 0; jj < 4; ++jj) {
        const int d = 4 * m + jj;
#pragma unroll
        for (int j = 0; j < 4; ++j) {
          const int o = d - 32 - j;
          if (o >= -32 && o <= 32) acc[j] = fmaf(LK65.v[o + 32], cv[jj], acc[j]);
        }
      }
    }
    *(float4*)(cb2 + base) = make_float4(acc[0], acc[1], acc[2], acc[3]);
    if (DOMAX) {
      float mm = fmaxf(fmaxf(fabsf(acc[0]), fabsf(acc[1])),
                       fmaxf(fabsf(acc[2]), fabsf(acc[3])));
      mm = wave_max(mm);
      if ((tid & 63) == 0) red2[tid >> 6] = mm;
    }
  }
  __syncthreads();
}

// ---------- kernel A: rho_unscaled (L2 of DWT rows) + per_token ----------
__global__ __launch_bounds__(256) void kA(const float* __restrict__ x,
                                          const float* __restrict__ wv,
                                          float* __restrict__ rho_us,
                                          float* __restrict__ pt) {
  const int blk = blockIdx.x;
  const int b = blk >> 8;
  const int g = blk & 255;
  const float* xb = x + (((size_t)b * NSEQ) + (size_t)g * 8) * 2048;
  const int tid = threadIdx.x;
  float sq[8] = {0.f, 0.f, 0.f, 0.f, 0.f, 0.f, 0.f, 0.f};
  float pp[8] = {0.f, 0.f, 0.f, 0.f, 0.f, 0.f, 0.f, 0.f};
  for (int c = tid * 4; c < 2048; c += 1024) {
    float4 w4 = *(const float4*)(wv + c);
    float wj[4] = {w4.x, w4.y, w4.z, w4.w};
    float xv[8][4];
#pragma unroll
    for (int r = 0; r < 8; ++r) {
      float4 t = *(const float4*)(xb + (size_t)r * 2048 + c);
      xv[r][0] = t.x; xv[r][1] = t.y; xv[r][2] = t.z; xv[r][3] = t.w;
    }
#pragma unroll
    for (int j = 0; j < 4; ++j) {
      float x0 = xv[0][j], x1 = xv[1][j], x2 = xv[2][j], x3 = xv[3][j];
      float x4 = xv[4][j], x5 = xv[5][j], x6 = xv[6][j], x7 = xv[7][j];
      float t01 = x0 + x1, t23 = x2 + x3, t45 = x4 + x5, t67 = x6 + x7;
      float a = t01 + t23, bb = t45 + t67;
      float c3 = a + bb, d3 = a - bb, d2a = t01 - t23, d2b = t45 - t67;
      float d10 = x0 - x1, d11 = x2 - x3, d12 = x4 - x5, d13 = x6 - x7;
      sq[0] += c3 * c3;  sq[1] += d3 * d3;  sq[2] += d2a * d2a; sq[3] += d2b * d2b;
      sq[4] += d10 * d10; sq[5] += d11 * d11; sq[6] += d12 * d12; sq[7] += d13 * d13;
      float w = wj[j];
      pp[0] += x0 * w; pp[1] += x1 * w; pp[2] += x2 * w; pp[3] += x3 * w;
      pp[4] += x4 * w; pp[5] += x5 * w; pp[6] += x6 * w; pp[7] += x7 * w;
    }
  }
  __shared__ float sred[4][16];
  float vals[16];
#pragma unroll
  for (int q = 0; q < 8; ++q) vals[q] = sq[q];
#pragma unroll
  for (int q = 0; q < 8; ++q) vals[8 + q] = pp[q];
#pragma unroll
  for (int q = 0; q < 16; ++q) vals[q] = wave_sum(vals[q]);
  int lane = tid & 63, wid = tid >> 6;
  if (lane == 0) {
#pragma unroll
    for (int q = 0; q < 16; ++q) sred[wid][q] = vals[q];
  }
  __syncthreads();
  if (tid < 16) {
    float s = sred[0][tid] + sred[1][tid] + sred[2][tid] + sred[3][tid];
    if (tid < 8) {
      float scale = (tid < 2) ? 0.125f : ((tid < 4) ? 0.25f : 0.5f);
      int pos = (tid == 0) ? g : (tid == 1) ? (256 + g)
               : (tid < 4) ? (512 + 2 * g + (tid - 2)) : (1024 + 4 * g + (tid - 4));
      rho_us[b * NSEQ + pos] = sqrtf(s * scale);
    } else {
      pt[b * NSEQ + 8 * g + (tid - 8)] = s;
    }
  }
}

// ---------- kernel B: serial dynamics; 1024 threads, EPT=2 ownership ----------
__global__ __launch_bounds__(NTB) void kB(const float* __restrict__ rho_us,
                                          const float* __restrict__ pt,
                                          const float* __restrict__ phi,
                                          float* __restrict__ rho_f) {
  extern __shared__ float sm[];
  float* cb    = sm;            // 2048   conv input
  float* cb2   = sm + 2048;     // 2048   conv output
  float* rhoM  = sm + 4096;     // 2048   rho mirror
  float* ymir  = sm + 6144;     // 3*2048 y[0..2] mirrors
  float* pairM = sm + 12288;    // 2*4096 (sgw,sg) interleaved, double-buffered by h&1
  float* red   = sm + 20480;    // 256
  float* red2  = sm + 20736;    // 16

  const int tid = threadIdx.x;
  const int b = blockIdx.x;
  const int e0 = 2 * tid;
  const int im1 = (e0 - 1) & (NSEQ - 1);
  const int ip2 = (e0 + 2) & (NSEQ - 1);
  int gen = 0;
  const float CFL_ = 0.4f;

  float2 ph2 = *(const float2*)(phi + e0);
  float phir[2] = {ph2.x, ph2.y};

  // ---- v = normalize(|dwt1d(per_token)| * sqrt(D)) ----
  float v_r[2];
  {
    const float* ptb = pt + b * NSEQ;
    float vl[2]; float part = 0.f;
#pragma unroll
    for (int j = 0; j < 2; ++j) {
      int s = e0 + j; float c;
      if (tid < 128) {
        int r = s * 8;
        float t01 = ptb[r] + ptb[r+1], t23 = ptb[r+2] + ptb[r+3];
        float t45 = ptb[r+4] + ptb[r+5], t67 = ptb[r+6] + ptb[r+7];
        c = ((t01 + t23) + (t45 + t67)) * INV2R2;
      } else if (tid < 256) {
        int r = (s - 256) * 8;
        float t01 = ptb[r] + ptb[r+1], t23 = ptb[r+2] + ptb[r+3];
        float t45 = ptb[r+4] + ptb[r+5], t67 = ptb[r+6] + ptb[r+7];
        c = ((t01 + t23) - (t45 + t67)) * INV2R2;
      } else if (tid < 512) {
        int r = (s - 512) * 4;
        c = ((ptb[r] + ptb[r+1]) - (ptb[r+2] + ptb[r+3])) * 0.5f;
      } else {
        int r = (s - 1024) * 2;
        c = (ptb[r] - ptb[r+1]) * INVR2;
      }
      float val = sqrtf(2048.0f * c * c) + EPSF;
      vl[j] = val; part += val;
    }
    float sv = block_sum(part, red, tid, gen);
    float inv = 1.0f / sv;
    v_r[0] = vl[0] * inv; v_r[1] = vl[1] * inv;
    *(float2*)(cb + e0) = make_float2(v_r[0], v_r[1]);   // v mirror (temp in cb)
  }
  // ---- rho = normalize(rho_us) ----
  float rho_r[2];
  {
    float2 rv = *(const float2*)(rho_us + b * NSEQ + e0);
    float rl0 = rv.x + EPSF, rl1 = rv.y + EPSF;
    float sr = block_sum(rl0 + rl1, red, tid, gen);      // barrier publishes cb
    float inv = 1.f / sr;
    rho_r[0] = rl0 * inv; rho_r[1] = rl1 * inv;
  }
  const float vp2c = cb[ip2];   // v[e0+2], cached forever (read before any cb overwrite)

  for (int k = 0; k < 3; ++k) {
    // ---- reaction ----
    {
      float tl[2]; float part = 0.f;
#pragma unroll
      for (int j = 0; j < 2; ++j) {
        float r = rho_r[j];
        float t = r * expf(-0.1f * (phir[j] + logf(r)));
        float t2 = fabsf(t) + EPSF;
        tl[j] = t2; part += t2;
      }
      float s = block_sum(part, red, tid, gen);
      float inv = 1.f / s;
      rho_r[0] = tl[0] * inv; rho_r[1] = tl[1] * inv;
      *(float2*)(rhoM + e0) = make_float2(rho_r[0], rho_r[1]);  // published by conv barrier
    }
    // ---- mpc: u = grad1(v) ----
    float u_r[2] = {v_r[1] - v_r[0], vp2c - v_r[1]};
    float up_r[2], y_r[4][2], ym1c[3], yp2c[3];

    for (int step = 0; step < 5; ++step) {
      conv_exec<true>(u_r[0], u_r[1], cb, cb2, red2, tid);   // up = leray(u) + max
      float2 upv = *(const float2*)(cb2 + e0);
      up_r[0] = upv.x; up_r[1] = upv.y;
      float um1c = cb2[im1];
      float rhom1c = rhoM[im1], rhop2c = rhoM[ip2];
      float4 r2a = *(float4*)(red2), r2b = *(float4*)(red2 + 4);
      float mx = fmaxf(fmaxf(fmaxf(r2a.x, r2a.y), fmaxf(r2a.z, r2a.w)),
                       fmaxf(fmaxf(r2b.x, r2b.y), fmaxf(r2b.z, r2b.w)));
      float dt = CFL_ / (mx + EPSF);
      // ---- forward rollout ----
      float sarr[4]; float spv = 1.f; float ntie = 1.f, dot = 0.f;
#pragma unroll
      for (int h = 0; h < 4; ++h) {
        float invp = 1.f / spv;
        if (h >= 1) {
          ym1c[h-1] = ymir[(h-1) * NSEQ + im1];
          yp2c[h-1] = ymir[(h-1) * NSEQ + ip2];
        }
        float rr[4];
        if (h == 0) { rr[0] = rhom1c; rr[1] = rho_r[0]; rr[2] = rho_r[1]; rr[3] = rhop2c; }
        else {
          rr[0] = (fabsf(ym1c[h-1]) + EPSF) * invp;
          rr[1] = (fabsf(y_r[h-1][0]) + EPSF) * invp;
          rr[2] = (fabsf(y_r[h-1][1]) + EPSF) * invp;
          rr[3] = (fabsf(yp2c[h-1]) + EPSF) * invp;
        }
        float part2 = 0.f, aux = 0.f;
#pragma unroll
        for (int j = 0; j < 2; ++j) {
          float ri = rr[j+1], rim1 = rr[j], rip1 = rr[j+2];
          float ui = up_r[j], um = j ? up_r[0] : um1c;
          float Fi = ui > 0.f ? ui * ri : ui * rip1;
          float Fm = um > 0.f ? um * rim1 : um * ri;
          float yv = ri - dt * (Fi - Fm);
          y_r[h][j] = yv;
          float ayv = fabsf(yv) + EPSF;
          part2 += ayv;
          if (h == 0) aux += (fabsf(ui) == mx) ? 1.f : 0.f;
          if (h == 3) aux += (1.f - v_r[j]) * 0.125f * ayv;
        }
        if (h < 3) *(float2*)(ymir + h * NSEQ + e0) = make_float2(y_r[h][0], y_r[h][1]);
        if (h == 3) {  // passA(3) mirrors before the h=3 barrier (wreg = initial)
          float sg0 = sgnf(y_r[3][0]), sg1 = sgnf(y_r[3][1]);
          float w0 = (1.f - v_r[0]) * 0.125f, w1 = (1.f - v_r[1]) * 0.125f;
          *(float4*)(pairM + 4096 + 2 * e0) = make_float4(sg0 * w0, sg0, sg1 * w1, sg1);
        }
        if (h == 0) { float o1, o2; block_sum2(part2, aux, red, tid, gen, o1, o2); sarr[0] = o1; ntie = o2; }
        else if (h == 3) { float o1, o2; block_sum2(part2, aux, red, tid, gen, o1, o2); sarr[3] = o1; dot = o2 / o1; }
        else sarr[h] = block_sum(part2, red, tid, gen);
        spv = sarr[h];
      }
      // ---- backward (passA folded into dot barriers via (sgw,sg) mirrors) ----
      float wreg[2] = {(1.f - v_r[0]) * 0.125f, (1.f - v_r[1]) * 0.125f};
      float upbar[2] = {0.f, 0.f};
      float dtb_part = 0.f;
#pragma unroll
      for (int h = 3; h >= 0; --h) {
        float invst = 1.f / sarr[h];
        float invp = (h > 0) ? 1.f / sarr[h-1] : 0.f;
        const int bo = (h & 1) * 4096;
        float yb_r[2];
#pragma unroll
        for (int j = 0; j < 2; ++j)
          yb_r[j] = sgnf(y_r[h][j]) * (wreg[j] - dot) * invst;
        float2 pm = *(const float2*)(pairM + bo + 2 * im1);
        float2 pp = *(const float2*)(pairM + bo + 2 * ip2);
        float ybm1 = (pm.x - dot * pm.y) * invst;
        float ybp2 = (pp.x - dot * pp.y) * invst;
        float rr[4];
        if (h == 0) { rr[0] = rhom1c; rr[1] = rho_r[0]; rr[2] = rho_r[1]; rr[3] = rhop2c; }
        else {
          rr[0] = (fabsf(ym1c[h-1]) + EPSF) * invp;
          rr[1] = (fabsf(y_r[h-1][0]) + EPSF) * invp;
          rr[2] = (fabsf(y_r[h-1][1]) + EPSF) * invp;
          rr[3] = (fabsf(yp2c[h-1]) + EPSF) * invp;
        }
        float dotn = 0.f;
#pragma unroll
        for (int j = 0; j < 2; ++j) {
          float ri = rr[j+1], rim1 = rr[j], rip1 = rr[j+2];
          float ui = up_r[j], um = j ? up_r[0] : um1c;
          float ybi = yb_r[j];
          float ybm = j ? yb_r[0] : ybm1;
          float ybp = (j < 1) ? yb_r[1] : ybp2;
          float Fbi = dt * (ybp - ybi);
          float Fbm = dt * (ybi - ybm);
          float wn = ybi;
          if (ui > 0.f)    wn += Fbi * ui;
          if (!(um > 0.f)) wn += Fbm * um;
          upbar[j] += Fbi * (ui > 0.f ? ri : rip1);
          float Fi = ui > 0.f ? ui * ri : ui * rip1;
          float Fm = um > 0.f ? um * rim1 : um * ri;
          dtb_part -= ybi * (Fi - Fm);
          if (h > 0) dotn += wn * ri;
          wreg[j] = wn;
        }
        if (h > 0) {
          const int bo2 = ((h - 1) & 1) * 4096;   // opposite buffer: no WAR race
          float sgA = sgnf(y_r[h-1][0]), sgB = sgnf(y_r[h-1][1]);
          *(float4*)(pairM + bo2 + 2 * e0) = make_float4(sgA * wreg[0], sgA, sgB * wreg[1], sgB);
          dot = block_sum(dotn, red, tid, gen);
        }
      }
      float dtbar = block_sum(dtb_part, red, tid, gen);
      float md = mx + EPSF;
      float mbar = dtbar * (-CFL_ / (md * md));
      float tiesc = mbar / ntie;
#pragma unroll
      for (int j = 0; j < 2; ++j) {
        float ui = up_r[j];
        if (fabsf(ui) == mx) upbar[j] += tiesc * sgnf(ui);
      }
      conv_exec<false>(upbar[0], upbar[1], cb, cb2, red2, tid);  // leray self-adjoint
      float2 lv = *(const float2*)(cb2 + e0);
      u_r[0] -= 0.1f * lv.x; u_r[1] -= 0.1f * lv.y;
    }
    // ---- outer: u = leray(u); dt; rho = normalize(advect(rho,u,dt,kappa)) ----
    conv_exec<true>(u_r[0], u_r[1], cb, cb2, red2, tid);
    float2 upv = *(const float2*)(cb2 + e0);
    up_r[0] = upv.x; up_r[1] = upv.y;
    float um1c = cb2[im1];
    float rhom1c = rhoM[im1], rhop2c = rhoM[ip2];
    float4 r2a = *(float4*)(red2), r2b = *(float4*)(red2 + 4);
    float mx = fmaxf(fmaxf(fmaxf(r2a.x, r2a.y), fmaxf(r2a.z, r2a.w)),
                     fmaxf(fmaxf(r2b.x, r2b.y), fmaxf(r2b.z, r2b.w)));
    float dt = CFL_ / (mx + EPSF);
    float kap = (k == 0) ? 0.01f : ((k == 1) ? 0.005f : 0.0f);
    float rr[4] = {rhom1c, rho_r[0], rho_r[1], rhop2c};
    float ylc[2]; float p2 = 0.f;
#pragma unroll
    for (int j = 0; j < 2; ++j) {
      float ri = rr[j+1], rim1 = rr[j], rip1 = rr[j+2];
      float ui = up_r[j], um = j ? up_r[0] : um1c;
      float Fi = ui > 0.f ? ui * ri : ui * rip1;
      float Fm = um > 0.f ? um * rim1 : um * ri;
      float yv = ri - dt * (Fi - Fm) + kap * dt * (rip1 + rim1 - 2.f * ri);
      ylc[j] = yv; p2 += fabsf(yv) + EPSF;
    }
    float s = block_sum(p2, red, tid, gen);
    float inv = 1.f / s;
    rho_r[0] = (fabsf(ylc[0]) + EPSF) * inv;
    rho_r[1] = (fabsf(ylc[1]) + EPSF) * inv;
  }
  // ---- final: rho_f = (rho + 0.1 v)/sum ----
  {
    float fl0 = rho_r[0] + 0.1f * v_r[0];
    float fl1 = rho_r[1] + 0.1f * v_r[1];
    float s = block_sum(fl0 + fl1, red, tid, gen);
    float inv = 1.f / s;
    *(float2*)(rho_f + b * NSEQ + e0) = make_float2(fl0 * inv, fl1 * inv);
  }
}

// ---------- kernel C: out = IDWT3(rho_f[:,:,None] * band_w[BAND_IDX]) ----------
__global__ __launch_bounds__(256) void kC(const float* __restrict__ rho_f,
                                          const float* __restrict__ bw,
                                          float* __restrict__ out) {
  const int blk = blockIdx.x;
  const int b = blk >> 8;
  const int g = blk & 255;
  __shared__ float q[8];
  if (threadIdx.x < 8) {
    int t = threadIdx.x;
    const float* rb = rho_f + b * NSEQ;
    float val;
    if (t == 0)      val = rb[g] * INV2R2;
    else if (t == 1) val = rb[256 + g] * INV2R2;
    else if (t < 4)  val = rb[512 + 2 * g + (t - 2)] * 0.5f;
    else             val = rb[1024 + 4 * g + (t - 4)] * INVR2;
    q[t] = val;
  }
  __syncthreads();
  float* ob = out + (((size_t)b * NSEQ) + (size_t)g * 8) * 2048;
  for (int c = threadIdx.x * 4; c < 2048; c += 1024) {
    float4 B0 = *(const float4*)(bw + c);
    float4 B1 = *(const float4*)(bw + 2048 + c);
    float4 B2 = *(const float4*)(bw + 4096 + c);
    float4 B3 = *(const float4*)(bw + 6144 + c);
    float b0[4] = {B0.x, B0.y, B0.z, B0.w};
    float b1[4] = {B1.x, B1.y, B1.z, B1.w};
    float b2[4] = {B2.x, B2.y, B2.z, B2.w};
    float b3[4] = {B3.x, B3.y, B3.z, B3.w};
    float o[8][4];
#pragma unroll
    for (int cc = 0; cc < 4; ++cc) {
      float pa = q[0] * b0[cc], pd3 = q[1] * b1[cc];
      float p2a = q[2] * b2[cc], p2b = q[3] * b2[cc];
      float e0 = pa + pd3, e1 = pa - pd3;
      float f0 = e0 + p2a, f1 = e0 - p2a, f2 = e1 + p2b, f3 = e1 - p2b;
      float g0 = q[4] * b3[cc], g1 = q[5] * b3[cc], g2 = q[6] * b3[cc], g3 = q[7] * b3[cc];
      o[0][cc] = f0 + g0; o[1][cc] = f0 - g0;
      o[2][cc] = f1 + g1; o[3][cc] = f1 - g1;
      o[4][cc] = f2 + g2; o[5][cc] = f2 - g2;
      o[6][cc] = f3 + g3; o[7][cc] = f3 - g3;
    }
#pragma unroll
    for (int j = 0; j < 8; ++j) {
      float4 t = make_float4(o[j][0], o[j][1], o[j][2], o[j][3]);
      *(float4*)(ob + (size_t)j * 2048 + c) = t;
    }
  }
}

#define SMEM_B (20752 * sizeof(float))   // 83,008 B dynamic LDS

extern "C" void kernel_launch(void* const* d_in, const int* in_sizes, int n_in,
                              void* d_out, int out_size, void* d_ws, size_t ws_size,
                              hipStream_t stream) {
  (void)in_sizes; (void)n_in; (void)out_size; (void)ws_size;
  const float* x   = (const float*)d_in[0];
  const float* wv  = (const float*)d_in[1];
  const float* phi = (const float*)d_in[2];
  const float* bw  = (const float*)d_in[3];
  float* out = (float*)d_out;
  float* rho_us = (float*)d_ws;
  float* pt     = rho_us + 8 * NSEQ;
  float* rho_f  = pt + 8 * NSEQ;

  hipFuncSetAttribute((const void*)kB, hipFuncAttributeMaxDynamicSharedMemorySize,
                      (int)SMEM_B);

  kA<<<dim3(2048), dim3(256), 0, stream>>>(x, wv, rho_us, pt);
  kB<<<dim3(8), dim3(NTB), SMEM_B, stream>>>(rho_us, pt, phi, rho_f);
  kC<<<dim3(2048), dim3(256), 0, stream>>>(rho_f, bw, out);
}

// Round 6
// 181.259 us; speedup vs baseline: 1.2031x; 1.2031x over previous
//
#include <hip/hip_runtime.h>
#include <math.h>

#define NSEQ 2048
#define EPSF 1e-8f
#define INV2R2 0.35355339059327373f
#define INVR2  0.7071067811865476f
#define NT 512           // kB: 8 waves, 2 per SIMD -> VGPR cap 128, no spill

// ---------- compile-time Leray conv taps (radius 32) ----------
// Jacobi: p_{n+1} = M p_n - 0.5 b, p_0=0, 50 iters => p = K*b, K circulant |j|<=49.
// leray(u) = conv(LK, u), LK_o = delta_o - (K_{o+1}-2K_o+K_{o-1}); symmetric.
// |LK_o| < ~3e-6 for |o|>32 -> radius-32 truncation error ~1e-8 (validated r5).
struct Taps65 { float v[65]; };

constexpr Taps65 make_taps65() {
  Taps65 t{};
  double K[99] = {};
  for (int j = -49; j <= 49; ++j) {
    int aj = j < 0 ? -j : j;
    double term = 1.0;
    for (int q = 0; q < aj; ++q) term *= 0.5;
    double sum = term;
    for (int i = aj + 2; i <= 49; i += 2) {
      int m = (i + j) / 2;
      term *= (double)((i - 1) * i) / (4.0 * (double)m * (double)(i - m));
      sum += term;
    }
    K[j + 49] = -0.5 * sum;
  }
  for (int o = -32; o <= 32; ++o) {
    double km1 = K[o - 1 + 49], k0 = K[o + 49], kp1 = K[o + 1 + 49];
    double T = kp1 - 2.0 * k0 + km1;
    t.v[o + 32] = (float)(((o == 0) ? 1.0 : 0.0) - T);
  }
  return t;
}
constexpr Taps65 LK65 = make_taps65();

// ---------- reduction helpers (512 threads = 8 waves) ----------
__device__ __forceinline__ float wave_sum(float x) {
#pragma unroll
  for (int m = 1; m < 64; m <<= 1) x += __shfl_xor(x, m, 64);
  return x;
}
__device__ __forceinline__ float wave_max(float x) {
#pragma unroll
  for (int m = 1; m < 64; m <<= 1) x = fmaxf(x, __shfl_xor(x, m, 64));
  return x;
}
__device__ __forceinline__ float block_sum(float x, float* red, int tid, int& gen) {
  float w = wave_sum(x);
  int slot = (gen & 7) << 5; gen++;
  if ((tid & 63) == 0) red[slot + (tid >> 6)] = w;
  __syncthreads();
  float4 a = *(float4*)(red + slot), b = *(float4*)(red + slot + 4);
  return ((a.x + a.y) + (a.z + a.w)) + ((b.x + b.y) + (b.z + b.w));
}
__device__ __forceinline__ void block_sum2(float a, float b, float* red, int tid, int& gen,
                                           float& oa, float& ob) {
  float wa = wave_sum(a), wb = wave_sum(b);
  int slot = (gen & 7) << 5; gen++;
  if ((tid & 63) == 0) { int w = tid >> 6; red[slot + w] = wa; red[slot + 16 + w] = wb; }
  __syncthreads();
  float4 a0 = *(float4*)(red + slot),      a1 = *(float4*)(red + slot + 4);
  float4 b0 = *(float4*)(red + slot + 16), b1 = *(float4*)(red + slot + 20);
  oa = ((a0.x + a0.y) + (a0.z + a0.w)) + ((a1.x + a1.y) + (a1.z + a1.w));
  ob = ((b0.x + b0.y) + (b0.z + b0.w)) + ((b1.x + b1.y) + (b1.z + b1.w));
}
__device__ __forceinline__ float sgnf(float x) {
  return (x > 0.f) ? 1.f : ((x < 0.f) ? -1.f : 0.f);
}

// ---------- 65-tap conv: regs in, regs out; double-buffered staging ----------
// 1 ds_write_b128 + 17 ds_read_b128 (contiguous, conflict-free) + 260 fmaf.
// No entry barrier: caller guarantees >=1 block barrier since last reads of cbuf.
__device__ __forceinline__ void conv65(const float in[4], float acc[4],
                                       float* __restrict__ cbuf, int tid) {
  *(float4*)(cbuf + (tid << 2)) = make_float4(in[0], in[1], in[2], in[3]);
  __syncthreads();
  const int base = tid << 2;
  acc[0] = 0.f; acc[1] = 0.f; acc[2] = 0.f; acc[3] = 0.f;
#pragma unroll
  for (int m = 0; m < 17; ++m) {
    const int idx = (base - 32 + 4 * m) & (NSEQ - 1);
    const float4 c4 = *(const float4*)(cbuf + idx);
    const float cv[4] = {c4.x, c4.y, c4.z, c4.w};
#pragma unroll
    for (int jj = 0; jj < 4; ++jj) {
      const int d = 4 * m + jj;
#pragma unroll
      for (int j = 0; j < 4; ++j) {
        const int o = d - 32 - j;
        if (o >= -32 && o <= 32) acc[j] = fmaf(LK65.v[o + 32], cv[jj], acc[j]);
      }
    }
  }
}

// ---------- kernel A: rho_unscaled (L2 of DWT rows) + per_token ----------
__global__ __launch_bounds__(256) void kA(const float* __restrict__ x,
                                          const float* __restrict__ wv,
                                          float* __restrict__ rho_us,
                                          float* __restrict__ pt) {
  const int blk = blockIdx.x;
  const int b = blk >> 8;
  const int g = blk & 255;
  const float* xb = x + (((size_t)b * NSEQ) + (size_t)g * 8) * 2048;
  const int tid = threadIdx.x;
  float sq[8] = {0.f, 0.f, 0.f, 0.f, 0.f, 0.f, 0.f, 0.f};
  float pp[8] = {0.f, 0.f, 0.f, 0.f, 0.f, 0.f, 0.f, 0.f};
  for (int c = tid * 4; c < 2048; c += 1024) {
    float4 w4 = *(const float4*)(wv + c);
    float wj[4] = {w4.x, w4.y, w4.z, w4.w};
    float xv[8][4];
#pragma unroll
    for (int r = 0; r < 8; ++r) {
      float4 t = *(const float4*)(xb + (size_t)r * 2048 + c);
      xv[r][0] = t.x; xv[r][1] = t.y; xv[r][2] = t.z; xv[r][3] = t.w;
    }
#pragma unroll
    for (int j = 0; j < 4; ++j) {
      float x0 = xv[0][j], x1 = xv[1][j], x2 = xv[2][j], x3 = xv[3][j];
      float x4 = xv[4][j], x5 = xv[5][j], x6 = xv[6][j], x7 = xv[7][j];
      float t01 = x0 + x1, t23 = x2 + x3, t45 = x4 + x5, t67 = x6 + x7;
      float a = t01 + t23, bb = t45 + t67;
      float c3 = a + bb, d3 = a - bb, d2a = t01 - t23, d2b = t45 - t67;
      float d10 = x0 - x1, d11 = x2 - x3, d12 = x4 - x5, d13 = x6 - x7;
      sq[0] += c3 * c3;  sq[1] += d3 * d3;  sq[2] += d2a * d2a; sq[3] += d2b * d2b;
      sq[4] += d10 * d10; sq[5] += d11 * d11; sq[6] += d12 * d12; sq[7] += d13 * d13;
      float w = wj[j];
      pp[0] += x0 * w; pp[1] += x1 * w; pp[2] += x2 * w; pp[3] += x3 * w;
      pp[4] += x4 * w; pp[5] += x5 * w; pp[6] += x6 * w; pp[7] += x7 * w;
    }
  }
  __shared__ float sred[4][16];
  float vals[16];
#pragma unroll
  for (int q = 0; q < 8; ++q) vals[q] = sq[q];
#pragma unroll
  for (int q = 0; q < 8; ++q) vals[8 + q] = pp[q];
#pragma unroll
  for (int q = 0; q < 16; ++q) vals[q] = wave_sum(vals[q]);
  int lane = tid & 63, wid = tid >> 6;
  if (lane == 0) {
#pragma unroll
    for (int q = 0; q < 16; ++q) sred[wid][q] = vals[q];
  }
  __syncthreads();
  if (tid < 16) {
    float s = sred[0][tid] + sred[1][tid] + sred[2][tid] + sred[3][tid];
    if (tid < 8) {
      float scale = (tid < 2) ? 0.125f : ((tid < 4) ? 0.25f : 0.5f);
      int pos = (tid == 0) ? g : (tid == 1) ? (256 + g)
               : (tid < 4) ? (512 + 2 * g + (tid - 2)) : (1024 + 4 * g + (tid - 4));
      rho_us[b * NSEQ + pos] = sqrtf(s * scale);
    } else {
      pt[b * NSEQ + 8 * g + (tid - 8)] = s;
    }
  }
}

// ---------- kernel B: serial dynamics; 512 threads, 4 contiguous elems/thread ----------
__global__ __launch_bounds__(NT, 2) void kB(const float* __restrict__ rho_us,
                                            const float* __restrict__ pt,
                                            const float* __restrict__ phi,
                                            float* __restrict__ rho_f) {
  __shared__ float cb[2][NSEQ];                 // conv staging, double-buffered
  __shared__ float vE0[NT];
  __shared__ float rhoE0[NT], rhoE3[NT];
  __shared__ float upE3[NT];
  __shared__ float yE0[3][NT], yE3[3][NT];
  __shared__ float4 pairE[2][NT];               // (sgw0,sg0,sgw3,sg3), by h-parity
  __shared__ float red[256];
  __shared__ float red2[8];

  const int tid = threadIdx.x;
  const int b = blockIdx.x;
  const int tm1 = (tid - 1) & (NT - 1);
  const int tp1 = (tid + 1) & (NT - 1);
  int gen = 0, cc = 0;
  const float CFL_ = 0.4f;

  float4 phv = *(const float4*)(phi + 4 * tid);
  float phir[4] = {phv.x, phv.y, phv.z, phv.w};

  // ---- v = normalize(|dwt1d(per_token)| * sqrt(D)) ----
  float v_r[4]; float vp4c;
  {
    const float* ptb = pt + b * NSEQ;
    float vl[4]; float part = 0.f;
#pragma unroll
    for (int j = 0; j < 4; ++j) {
      float c;
      if (tid < 64) {
        int r = (4 * tid + j) * 8;
        float t01 = ptb[r] + ptb[r+1], t23 = ptb[r+2] + ptb[r+3];
        float t45 = ptb[r+4] + ptb[r+5], t67 = ptb[r+6] + ptb[r+7];
        c = ((t01 + t23) + (t45 + t67)) * INV2R2;
      } else if (tid < 128) {
        int r = (4 * (tid - 64) + j) * 8;
        float t01 = ptb[r] + ptb[r+1], t23 = ptb[r+2] + ptb[r+3];
        float t45 = ptb[r+4] + ptb[r+5], t67 = ptb[r+6] + ptb[r+7];
        c = ((t01 + t23) - (t45 + t67)) * INV2R2;
      } else if (tid < 256) {
        int r = (4 * (tid - 128) + j) * 4;
        c = ((ptb[r] + ptb[r+1]) - (ptb[r+2] + ptb[r+3])) * 0.5f;
      } else {
        int r = (4 * (tid - 256) + j) * 2;
        c = (ptb[r] - ptb[r+1]) * INVR2;
      }
      float val = sqrtf(2048.0f * c * c) + EPSF;
      vl[j] = val; part += val;
    }
    float sv = block_sum(part, red, tid, gen);
    float inv = 1.0f / sv;
#pragma unroll
    for (int j = 0; j < 4; ++j) v_r[j] = vl[j] * inv;
    vE0[tid] = v_r[0];
  }
  // ---- rho = normalize(rho_us) ----
  float rho_r[4];
  {
    float4 rv = *(const float4*)(rho_us + b * NSEQ + 4 * tid);
    float rl[4] = {rv.x + EPSF, rv.y + EPSF, rv.z + EPSF, rv.w + EPSF};
    float part = rl[0] + rl[1] + rl[2] + rl[3];
    float sr = block_sum(part, red, tid, gen);   // barrier publishes vE0
    float inv = 1.f / sr;
#pragma unroll
    for (int j = 0; j < 4; ++j) rho_r[j] = rl[j] * inv;
  }
  vp4c = vE0[tp1];   // v never changes; cache once

  for (int k = 0; k < 3; ++k) {
    // ---- reaction ----
    {
      float tl[4]; float part = 0.f;
#pragma unroll
      for (int j = 0; j < 4; ++j) {
        float r = rho_r[j];
        float t = r * expf(-0.1f * (phir[j] + logf(r)));
        float t2 = fabsf(t) + EPSF;
        tl[j] = t2; part += t2;
      }
      float s = block_sum(part, red, tid, gen);
      float inv = 1.f / s;
#pragma unroll
      for (int j = 0; j < 4; ++j) rho_r[j] = tl[j] * inv;
      rhoE0[tid] = rho_r[0]; rhoE3[tid] = rho_r[3];  // published by conv1 barriers
    }
    // ---- mpc: u = grad1(v) (registers only) ----
    float u_r[4];
    u_r[0] = v_r[1] - v_r[0]; u_r[1] = v_r[2] - v_r[1];
    u_r[2] = v_r[3] - v_r[2]; u_r[3] = vp4c - v_r[3];

    float up_r[4], y_r[4][4], ym1c[3], yp4c2[3];
    for (int step = 0; step < 5; ++step) {
      // ---- up = leray(u), wave-max folded; publish edge + max ----
      conv65(u_r, up_r, cb[(cc++) & 1], tid);
      upE3[tid] = up_r[3];
      {
        float mm = fmaxf(fmaxf(fabsf(up_r[0]), fabsf(up_r[1])),
                         fmaxf(fabsf(up_r[2]), fabsf(up_r[3])));
        mm = wave_max(mm);
        if ((tid & 63) == 0) red2[tid >> 6] = mm;
      }
      __syncthreads();
      float4 r2a = *(float4*)(red2), r2b = *(float4*)(red2 + 4);
      float mx = fmaxf(fmaxf(fmaxf(r2a.x, r2a.y), fmaxf(r2a.z, r2a.w)),
                       fmaxf(fmaxf(r2b.x, r2b.y), fmaxf(r2b.z, r2b.w)));
      float um1 = upE3[tm1];
      float rhom1 = rhoE3[tm1], rhop4 = rhoE0[tp1];
      float dt = CFL_ / (mx + EPSF);
      // ---- forward rollout (ntie in h=0, cost-dot in h=3, passA(3) mirrored) ----
      float sarr[4]; float spv = 1.f; float ntie = 1.f, dot = 0.f;
#pragma unroll
      for (int h = 0; h < 4; ++h) {
        float invp = 1.f / spv;
        if (h >= 1) { ym1c[h-1] = yE3[h-1][tm1]; yp4c2[h-1] = yE0[h-1][tp1]; }
        float rr[6];
        if (h == 0) {
          rr[0] = rhom1; rr[1] = rho_r[0]; rr[2] = rho_r[1];
          rr[3] = rho_r[2]; rr[4] = rho_r[3]; rr[5] = rhop4;
        } else {
          rr[0] = (fabsf(ym1c[h-1]) + EPSF) * invp;
#pragma unroll
          for (int j = 0; j < 4; ++j) rr[j+1] = (fabsf(y_r[h-1][j]) + EPSF) * invp;
          rr[5] = (fabsf(yp4c2[h-1]) + EPSF) * invp;
        }
        float part2 = 0.f, aux = 0.f;
#pragma unroll
        for (int j = 0; j < 4; ++j) {
          float ri = rr[j+1], rim1 = rr[j], rip1 = rr[j+2];
          float ui = up_r[j], um = j ? up_r[j-1] : um1;
          float Fi = ui > 0.f ? ui * ri : ui * rip1;
          float Fm = um > 0.f ? um * rim1 : um * ri;
          float yv = ri - dt * (Fi - Fm);
          y_r[h][j] = yv;
          float ayv = fabsf(yv) + EPSF;
          part2 += ayv;
          if (h == 0) aux += (fabsf(ui) == mx) ? 1.f : 0.f;
          if (h == 3) aux += (1.f - v_r[j]) * 0.125f * ayv;
        }
        if (h < 3) { yE0[h][tid] = y_r[h][0]; yE3[h][tid] = y_r[h][3]; }
        if (h == 3) {
          float sg0 = sgnf(y_r[3][0]), sg3 = sgnf(y_r[3][3]);
          pairE[1][tid] = make_float4(sg0 * (1.f - v_r[0]) * 0.125f, sg0,
                                      sg3 * (1.f - v_r[3]) * 0.125f, sg3);
        }
        if (h == 0) { float o1, o2; block_sum2(part2, aux, red, tid, gen, o1, o2); sarr[0] = o1; ntie = o2; }
        else if (h == 3) { float o1, o2; block_sum2(part2, aux, red, tid, gen, o1, o2); sarr[3] = o1; dot = o2 / o1; }
        else sarr[h] = block_sum(part2, red, tid, gen);
        spv = sarr[h];
      }
      // ---- backward (passA folded into dot barriers via pairE mirrors) ----
      float wreg[4], upbar[4];
#pragma unroll
      for (int j = 0; j < 4; ++j) { wreg[j] = (1.f - v_r[j]) * 0.125f; upbar[j] = 0.f; }
      float dtb_part = 0.f;
#pragma unroll
      for (int h = 3; h >= 0; --h) {
        float invst = 1.f / sarr[h];
        float invp = (h > 0) ? 1.f / sarr[h-1] : 0.f;
        const int bo = h & 1;
        float yb_r[4];
#pragma unroll
        for (int j = 0; j < 4; ++j)
          yb_r[j] = sgnf(y_r[h][j]) * (wreg[j] - dot) * invst;
        float4 pm = pairE[bo][tm1], pp = pairE[bo][tp1];
        float ybm1 = (pm.z - dot * pm.w) * invst;
        float ybp4 = (pp.x - dot * pp.y) * invst;
        float rr[6];
        if (h == 0) {
          rr[0] = rhom1; rr[1] = rho_r[0]; rr[2] = rho_r[1];
          rr[3] = rho_r[2]; rr[4] = rho_r[3]; rr[5] = rhop4;
        } else {
          rr[0] = (fabsf(ym1c[h-1]) + EPSF) * invp;
#pragma unroll
          for (int j = 0; j < 4; ++j) rr[j+1] = (fabsf(y_r[h-1][j]) + EPSF) * invp;
          rr[5] = (fabsf(yp4c2[h-1]) + EPSF) * invp;
        }
        float dotn = 0.f;
#pragma unroll
        for (int j = 0; j < 4; ++j) {
          float ri = rr[j+1], rim1 = rr[j], rip1 = rr[j+2];
          float ui = up_r[j], um = j ? up_r[j-1] : um1;
          float ybi = yb_r[j];
          float ybm = j ? yb_r[j-1] : ybm1;
          float ybp = (j < 3) ? yb_r[j+1] : ybp4;
          float Fbi = dt * (ybp - ybi);
          float Fbm = dt * (ybi - ybm);
          float wn = ybi;
          if (ui > 0.f)    wn += Fbi * ui;
          if (!(um > 0.f)) wn += Fbm * um;
          upbar[j] += Fbi * (ui > 0.f ? ri : rip1);
          float Fi = ui > 0.f ? ui * ri : ui * rip1;
          float Fm = um > 0.f ? um * rim1 : um * ri;
          dtb_part -= ybi * (Fi - Fm);
          if (h > 0) dotn += wn * ri;
          wreg[j] = wn;
        }
        if (h > 0) {
          float sgA = sgnf(y_r[h-1][0]), sgB = sgnf(y_r[h-1][3]);
          pairE[(h - 1) & 1][tid] = make_float4(sgA * wreg[0], sgA, sgB * wreg[3], sgB);
          dot = block_sum(dotn, red, tid, gen);
        }
      }
      float dtbar = block_sum(dtb_part, red, tid, gen);
      float md = mx + EPSF;
      float mbar = dtbar * (-CFL_ / (md * md));
      float tiesc = mbar / ntie;
#pragma unroll
      for (int j = 0; j < 4; ++j) {
        float ui = up_r[j];
        if (fabsf(ui) == mx) upbar[j] += tiesc * sgnf(ui);
      }
      // ---- u -= 0.1 * leray(upbar) (self-adjoint); no publish needed ----
      float accv[4];
      conv65(upbar, accv, cb[(cc++) & 1], tid);
#pragma unroll
      for (int j = 0; j < 4; ++j) u_r[j] -= 0.1f * accv[j];
    }
    // ---- outer: u = leray(u); dt; rho = normalize(advect(rho,u,dt,kappa)) ----
    conv65(u_r, up_r, cb[(cc++) & 1], tid);
    upE3[tid] = up_r[3];
    {
      float mm = fmaxf(fmaxf(fabsf(up_r[0]), fabsf(up_r[1])),
                       fmaxf(fabsf(up_r[2]), fabsf(up_r[3])));
      mm = wave_max(mm);
      if ((tid & 63) == 0) red2[tid >> 6] = mm;
    }
    __syncthreads();
    float4 r2a = *(float4*)(red2), r2b = *(float4*)(red2 + 4);
    float mx = fmaxf(fmaxf(fmaxf(r2a.x, r2a.y), fmaxf(r2a.z, r2a.w)),
                     fmaxf(fmaxf(r2b.x, r2b.y), fmaxf(r2b.z, r2b.w)));
    float um1 = upE3[tm1];
    float rhom1 = rhoE3[tm1], rhop4 = rhoE0[tp1];
    float dt = CFL_ / (mx + EPSF);
    float kap = (k == 0) ? 0.01f : ((k == 1) ? 0.005f : 0.0f);
    float rr[6];
    rr[0] = rhom1; rr[1] = rho_r[0]; rr[2] = rho_r[1];
    rr[3] = rho_r[2]; rr[4] = rho_r[3]; rr[5] = rhop4;
    float ylc[4]; float p2 = 0.f;
#pragma unroll
    for (int j = 0; j < 4; ++j) {
      float ri = rr[j+1], rim1 = rr[j], rip1 = rr[j+2];
      float ui = up_r[j], um = j ? up_r[j-1] : um1;
      float Fi = ui > 0.f ? ui * ri : ui * rip1;
      float Fm = um > 0.f ? um * rim1 : um * ri;
      float yv = ri - dt * (Fi - Fm) + kap * dt * (rip1 + rim1 - 2.f * ri);
      ylc[j] = yv; p2 += fabsf(yv) + EPSF;
    }
    float s = block_sum(p2, red, tid, gen);
    float inv = 1.f / s;
#pragma unroll
    for (int j = 0; j < 4; ++j) rho_r[j] = (fabsf(ylc[j]) + EPSF) * inv;
    rhoE0[tid] = rho_r[0]; rhoE3[tid] = rho_r[3];
  }
  // ---- final: rho_f = (rho + 0.1 v)/sum ----
  {
    float fl[4]; float part = 0.f;
#pragma unroll
    for (int j = 0; j < 4; ++j) {
      float f = rho_r[j] + 0.1f * v_r[j];
      fl[j] = f; part += f;
    }
    float s = block_sum(part, red, tid, gen);
    float inv = 1.f / s;
    *(float4*)(rho_f + b * NSEQ + 4 * tid) =
        make_float4(fl[0] * inv, fl[1] * inv, fl[2] * inv, fl[3] * inv);
  }
}

// ---------- kernel C: out = IDWT3(rho_f[:,:,None] * band_w[BAND_IDX]) ----------
__global__ __launch_bounds__(256) void kC(const float* __restrict__ rho_f,
                                          const float* __restrict__ bw,
                                          float* __restrict__ out) {
  const int blk = blockIdx.x;
  const int b = blk >> 8;
  const int g = blk & 255;
  __shared__ float q[8];
  if (threadIdx.x < 8) {
    int t = threadIdx.x;
    const float* rb = rho_f + b * NSEQ;
    float val;
    if (t == 0)      val = rb[g] * INV2R2;
    else if (t == 1) val = rb[256 + g] * INV2R2;
    else if (t < 4)  val = rb[512 + 2 * g + (t - 2)] * 0.5f;
    else             val = rb[1024 + 4 * g + (t - 4)] * INVR2;
    q[t] = val;
  }
  __syncthreads();
  float* ob = out + (((size_t)b * NSEQ) + (size_t)g * 8) * 2048;
  for (int c = threadIdx.x * 4; c < 2048; c += 1024) {
    float4 B0 = *(const float4*)(bw + c);
    float4 B1 = *(const float4*)(bw + 2048 + c);
    float4 B2 = *(const float4*)(bw + 4096 + c);
    float4 B3 = *(const float4*)(bw + 6144 + c);
    float b0[4] = {B0.x, B0.y, B0.z, B0.w};
    float b1[4] = {B1.x, B1.y, B1.z, B1.w};
    float b2[4] = {B2.x, B2.y, B2.z, B2.w};
    float b3[4] = {B3.x, B3.y, B3.z, B3.w};
    float o[8][4];
#pragma unroll
    for (int cc = 0; cc < 4; ++cc) {
      float pa = q[0] * b0[cc], pd3 = q[1] * b1[cc];
      float p2a = q[2] * b2[cc], p2b = q[3] * b2[cc];
      float e0 = pa + pd3, e1 = pa - pd3;
      float f0 = e0 + p2a, f1 = e0 - p2a, f2 = e1 + p2b, f3 = e1 - p2b;
      float g0 = q[4] * b3[cc], g1 = q[5] * b3[cc], g2 = q[6] * b3[cc], g3 = q[7] * b3[cc];
      o[0][cc] = f0 + g0; o[1][cc] = f0 - g0;
      o[2][cc] = f1 + g1; o[3][cc] = f1 - g1;
      o[4][cc] = f2 + g2; o[5][cc] = f2 - g2;
      o[6][cc] = f3 + g3; o[7][cc] = f3 - g3;
    }
#pragma unroll
    for (int j = 0; j < 8; ++j) {
      float4 t = make_float4(o[j][0], o[j][1], o[j][2], o[j][3]);
      *(float4*)(ob + (size_t)j * 2048 + c) = t;
    }
  }
}

extern "C" void kernel_launch(void* const* d_in, const int* in_sizes, int n_in,
                              void* d_out, int out_size, void* d_ws, size_t ws_size,
                              hipStream_t stream) {
  (void)in_sizes; (void)n_in; (void)out_size; (void)ws_size;
  const float* x   = (const float*)d_in[0];
  const float* wv  = (const float*)d_in[1];
  const float* phi = (const float*)d_in[2];
  const float* bw  = (const float*)d_in[3];
  float* out = (float*)d_out;
  float* rho_us = (float*)d_ws;
  float* pt     = rho_us + 8 * NSEQ;
  float* rho_f  = pt + 8 * NSEQ;

  kA<<<dim3(2048), dim3(256), 0, stream>>>(x, wv, rho_us, pt);
  kB<<<dim3(8), dim3(NT), 0, stream>>>(rho_us, pt, phi, rho_f);
  kC<<<dim3(2048), dim3(256), 0, stream>>>(rho_f, bw, out);
}